// Round 9
// baseline (505.822 us; speedup 1.0000x reference)
//
#include <hip/hip_runtime.h>

#define N_NODES 100000
#define N_EDGES 1600000
#define F 16

#define NPB   32            // nodes per bucket
#define NB    3125          // buckets: NB*NPB == N_NODES exactly
#define NBPAD 3200          // padded bin-array length

// ws layout (dword units):
//   rec     : [0, N_EDGES*4)        float4 records {col, ax, ay, dest} (25.6 MB)
//   hist    : +REC_DW  [0, NBPAD)
//   offsets : +NBPAD   [0, NBPAD)   (offsets[NB] = N_EDGES)
//   cursor  : +NBPAD   [0, NBPAD)
#define REC_DW (N_EDGES * 4)

typedef __attribute__((ext_vector_type(8))) short bf16x8;  // 8 bf16 (4 VGPRs)
typedef __attribute__((ext_vector_type(4))) float f32x4;   // MFMA C/D

// pack two f32 -> one dword of 2 bf16 (RNE), single instruction.
__device__ __forceinline__ unsigned pk_bf16(float lo, float hi) {
    unsigned r;
    asm("v_cvt_pk_bf16_f32 %0, %1, %2" : "=v"(r) : "v"(lo), "v"(hi));
    return r;
}

__global__ __launch_bounds__(256) void zero_hist_kernel(unsigned* __restrict__ hist) {
    int i = blockIdx.x * 256 + threadIdx.x;
    if (i < NBPAD) hist[i] = 0u;
}

__global__ __launch_bounds__(256) void hist_kernel(const int* __restrict__ ei,
                                                   unsigned* __restrict__ hist) {
    const int stride = gridDim.x * 256;
    for (int e = blockIdx.x * 256 + threadIdx.x; e < N_EDGES; e += stride)
        atomicAdd(&hist[((unsigned)ei[e]) >> 5], 1u);
}

// Exclusive scan of NB bins, single 1024-thread block (4 bins/thread).
__global__ __launch_bounds__(1024) void scan_kernel(const unsigned* __restrict__ hist,
                                                    unsigned* __restrict__ offs,
                                                    unsigned* __restrict__ cur) {
    __shared__ unsigned lds[1024];
    const int t = threadIdx.x;
    unsigned c[4]; unsigned s = 0;
#pragma unroll
    for (int k = 0; k < 4; ++k) {
        const int b = t * 4 + k;
        c[k] = (b < NB) ? hist[b] : 0u;
        s += c[k];
    }
    lds[t] = s;
    __syncthreads();
    for (int off = 1; off < 1024; off <<= 1) {       // Hillis-Steele inclusive
        unsigned v = (t >= off) ? lds[t - off] : 0u;
        __syncthreads();
        lds[t] += v;
        __syncthreads();
    }
    unsigned run = (t == 0) ? 0u : lds[t - 1];
#pragma unroll
    for (int k = 0; k < 4; ++k) {
        const int b = t * 4 + k;
        if (b < NB) { offs[b] = run; cur[b] = run; run += c[k]; }
    }
    if (t == 1023) offs[NB] = run;                   // == N_EDGES
}

__global__ __launch_bounds__(256) void scatter_kernel(const int* __restrict__ ei,
                                                      const float2* __restrict__ attr,
                                                      unsigned* __restrict__ cur,
                                                      float4* __restrict__ rec) {
    const int stride = gridDim.x * 256;
    for (int e = blockIdx.x * 256 + threadIdx.x; e < N_EDGES; e += stride) {
        const int dest = ei[e];
        const int col  = ei[N_EDGES + e];
        const float2 a = attr[e];
        const unsigned p = atomicAdd(&cur[((unsigned)dest) >> 5], 1u);
        rec[p] = make_float4(__int_as_float(col), a.x, a.y, __int_as_float(dest));
    }
}

// r3-r8 established: f32 dword atomics pin at 1/channel/cycle (25.6M -> 89us);
// all wider/packed atomic formats are slower microcoded paths. This kernel has
// ZERO global atomics: edges are bucket-sorted by dest (32 nodes/bucket), each
// bucket owned by exactly one block, accumulation in a 2KB LDS f32 tile via
// ds_add, final 512-dword coalesced plain store. MFMA math identical to r6's
// verified swapped form (D = W*X; lane holds features c*4..c*4+3 of edge e15).
__global__ __launch_bounds__(256, 4) void conv_bucket(
    const float* __restrict__ x,          // [N_NODES, 16]
    const float4* __restrict__ rec,       // sorted records
    const unsigned* __restrict__ offs,    // [NB+1]
    const float* __restrict__ weight,     // [4,4,16,16] = [cell][i][f]
    float* __restrict__ out)              // [N_NODES, 16]
{
    __shared__ float accs[NPB * F];       // 2 KB

    const int lane = threadIdx.x & 63;
    const int wid  = threadIdx.x >> 6;
    const int e15  = lane & 15;        // B col: edge within 16-edge unit
    const int fo   = lane & 15;        // A row: output feature (weight frag)
    const int c    = lane >> 4;        // K-chunk 0..3
    const int hv   = c >> 1;
    const int i0   = (c & 1) * 8;

    // A fragments (weights), loaded once. MFMA m covers cells 2m, 2m+1.
    bf16x8 bw[8];
#pragma unroll
    for (int m = 0; m < 8; ++m) {
        const float* wp = weight + (2 * m + hv) * 256 + i0 * 16 + fo;
        union { bf16x8 v; unsigned w[4]; } bb;
#pragma unroll
        for (int p = 0; p < 4; ++p)
            bb.w[p] = pk_bf16(wp[(2 * p) * 16], wp[(2 * p + 1) * 16]);
        bw[m] = bb.v;
    }

    const int b    = blockIdx.x;
    const int base = b * NPB;
    const unsigned start = offs[b];
    const unsigned end   = offs[b + 1];

    for (int i = threadIdx.x; i < NPB * F; i += 256) accs[i] = 0.f;
    __syncthreads();

    // wave-interleaved chunks of 32 edges (2 x 16-edge MFMA units)
    for (unsigned eb = start + wid * 32; eb < end; eb += 128) {
        int   ln[2]; float vm[2]; float2 at[2]; int col[2];
#pragma unroll
        for (int u = 0; u < 2; ++u) {
            const unsigned idx = eb + u * 16 + e15;
            const bool valid = idx < end;
            const float4 r = rec[valid ? idx : start];
            col[u] = __float_as_int(r.x);
            at[u]  = make_float2(r.y, r.z);
            const int local = (__float_as_int(r.w) - base) & (NPB - 1);
            ln[u] = valid ? local : 0;
            vm[u] = valid ? 1.f : 0.f;
        }

        // x gather (this lane's K-chunk of edge e15's source node)
        float4 xa[2], xb[2];
#pragma unroll
        for (int u = 0; u < 2; ++u) {
            const float4* xv = (const float4*)(x + (size_t)col[u] * 16 + i0);
            xa[u] = xv[0]; xb[u] = xv[1];
        }

        // basis factors (invalid lanes masked to t = 0)
        float bu_[2][4], bvE_[2], bvO_[2];
#pragma unroll
        for (int u = 0; u < 2; ++u) {
            float fu = (at[u].x + 1.0f) * 1.5f;
            int iu = (int)fu; iu = iu < 0 ? 0 : (iu > 2 ? 2 : iu);
            const float wu1 = fu - (float)iu, wu0 = 1.0f - wu1;
            float fv = (at[u].y + 1.0f) * 1.5f;
            int iv = (int)fv; iv = iv < 0 ? 0 : (iv > 2 ? 2 : iv);
            const float wv1 = fv - (float)iv, wv0 = 1.0f - wv1;

            bu_[u][0] = iu == 0 ? wu0 : 0.f;
            bu_[u][1] = iu == 0 ? wu1 : (iu == 1 ? wu0 : 0.f);
            bu_[u][2] = iu == 2 ? wu0 : (iu == 1 ? wu1 : 0.f);
            bu_[u][3] = iu == 2 ? wu1 : 0.f;
            const float bv0 = iv == 0 ? wv0 : 0.f;
            const float bv1 = iv == 0 ? wv1 : (iv == 1 ? wv0 : 0.f);
            const float bv2 = iv == 2 ? wv0 : (iv == 1 ? wv1 : 0.f);
            const float bv3 = iv == 2 ? wv1 : 0.f;
            bvE_[u] = (hv ? bv1 : bv0) * vm[u];
            bvO_[u] = (hv ? bv3 : bv2) * vm[u];
        }

        // 16 MFMAs, 4 independent chains; D = W(16f x 32K) * X(32K x 16e)
        f32x4 accE[2] = {{0.f,0.f,0.f,0.f},{0.f,0.f,0.f,0.f}};
        f32x4 accO[2] = {{0.f,0.f,0.f,0.f},{0.f,0.f,0.f,0.f}};
#pragma unroll
        for (int m = 0; m < 8; ++m) {
#pragma unroll
            for (int u = 0; u < 2; ++u) {
                const float t = bu_[u][m >> 1] * ((m & 1) ? bvO_[u] : bvE_[u]);
                union { bf16x8 v; unsigned w[4]; } aa;
                aa.w[0] = pk_bf16(t * xa[u].x, t * xa[u].y);
                aa.w[1] = pk_bf16(t * xa[u].z, t * xa[u].w);
                aa.w[2] = pk_bf16(t * xb[u].x, t * xb[u].y);
                aa.w[3] = pk_bf16(t * xb[u].z, t * xb[u].w);
                if (m & 1)
                    accO[u] = __builtin_amdgcn_mfma_f32_16x16x32_bf16(bw[m], aa.v, accO[u], 0, 0, 0);
                else
                    accE[u] = __builtin_amdgcn_mfma_f32_16x16x32_bf16(bw[m], aa.v, accE[u], 0, 0, 0);
            }
        }

        // accumulate in LDS (invalid lanes add 0 to node 0)
#pragma unroll
        for (int u = 0; u < 2; ++u) {
            const f32x4 acc = accE[u] + accO[u];
            float* p = &accs[ln[u] * F + c * 4];
            atomicAdd(p + 0, acc.x);
            atomicAdd(p + 1, acc.y);
            atomicAdd(p + 2, acc.z);
            atomicAdd(p + 3, acc.w);
        }
    }

    __syncthreads();
    // plain coalesced store of this block's exclusive 32-node slice
    for (int i = threadIdx.x; i < NPB * F; i += 256)
        out[(size_t)base * F + i] = accs[i];
}

extern "C" void kernel_launch(void* const* d_in, const int* in_sizes, int n_in,
                              void* d_out, int out_size, void* d_ws, size_t ws_size,
                              hipStream_t stream) {
    const float* x  = (const float*)d_in[0];
    const int*   ei = (const int*)d_in[1];
    const float* ea = (const float*)d_in[2];
    const float* w  = (const float*)d_in[3];
    float* out = (float*)d_out;
    (void)out_size; (void)ws_size; (void)in_sizes; (void)n_in;

    float4*   rec  = (float4*)d_ws;
    unsigned* hist = (unsigned*)d_ws + REC_DW;
    unsigned* offs = hist + NBPAD;
    unsigned* cur  = offs + NBPAD;

    zero_hist_kernel<<<(NBPAD + 255) / 256, 256, 0, stream>>>(hist);
    hist_kernel<<<2048, 256, 0, stream>>>(ei, hist);
    scan_kernel<<<1, 1024, 0, stream>>>(hist, offs, cur);
    scatter_kernel<<<2048, 256, 0, stream>>>(ei, (const float2*)ea, cur, rec);
    conv_bucket<<<NB, 256, 0, stream>>>(x, rec, offs, w, out);
}

// Round 10
// 477.722 us; speedup vs baseline: 1.0588x; 1.0588x over previous
//
#include <hip/hip_runtime.h>

#define N_NODES 100000
#define N_EDGES 1600000
#define F 16

#define NPB 64                    // nodes per bin
#define NB  1563                  // ceil(N_NODES / NPB)
#define CAP 1280                  // mean 1024 + 8 sigma -> deterministic fit (guarded)

typedef __attribute__((ext_vector_type(8))) short bf16x8;  // 8 bf16 (4 VGPRs)
typedef __attribute__((ext_vector_type(4))) float f32x4;   // MFMA C/D

// pack two f32 -> one dword of 2 bf16 (RNE), single instruction.
__device__ __forceinline__ unsigned pk_bf16(float lo, float hi) {
    unsigned r;
    asm("v_cvt_pk_bf16_f32 %0, %1, %2" : "=v"(r) : "v"(lo), "v"(hi));
    return r;
}
// pack two f32 -> two f16 (RTZ) in one dword.
__device__ __forceinline__ unsigned pk_f16(float lo, float hi) {
    unsigned r;
    asm("v_cvt_pkrtz_f16_f32 %0, %1, %2" : "=v"(r) : "v"(lo), "v"(hi));
    return r;
}
// low 16 bits of h as f16 -> f32
__device__ __forceinline__ float f16lo(unsigned h) {
    float f;
    asm("v_cvt_f32_f16 %0, %1" : "=v"(f) : "v"(h));
    return f;
}

__global__ __launch_bounds__(256) void zero_cur_kernel(unsigned* __restrict__ cur) {
    int i = blockIdx.x * 256 + threadIdx.x;
    if (i < NB) cur[i] = 0u;
}

// r9 post-mortem: hist+scan+16B-record scatter cost ~350us. This scatter is the
// ONLY grouping pass: fixed per-bin capacity (no hist/scan), 8B records
// {col | loc<<17, f16x2 attr}. 1.6M cursor atomics over 1563 addresses ~= 5us.
__global__ __launch_bounds__(256) void scatter_kernel(const int* __restrict__ ei,
                                                      const float2* __restrict__ attr,
                                                      unsigned* __restrict__ cur,
                                                      uint2* __restrict__ rec) {
    const int stride = gridDim.x * 256;
    for (int e = blockIdx.x * 256 + threadIdx.x; e < N_EDGES; e += stride) {
        const unsigned dest = (unsigned)ei[e];
        const unsigned col  = (unsigned)ei[N_EDGES + e];
        const float2 a = attr[e];
        const unsigned bin = dest >> 6;
        const unsigned loc = dest & 63u;
        const unsigned ha  = pk_f16(a.x, a.y);
        const unsigned p = atomicAdd(&cur[bin], 1u);
        if (p < CAP)                                    // never triggers (8-sigma)
            rec[(size_t)bin * CAP + p] = make_uint2(col | (loc << 17), ha);
    }
}

// Zero global atomics (r3-r8: 25.6M dword atomics pin at 1/channel/cycle=83us;
// all packed/wide atomic formats are slower microcoded paths). Each block owns
// a 64-node bin: r5-style pipelined edge loop (rec 2-deep, x 1-deep prefetch
// -- r9's conv ran at HALF rate without it), MFMA math identical to the
// r6/r9-verified swapped form (D = W*X; lane holds features c*4..+3 of edge
// e15), accumulation via LDS f32 atomics (bank-swizzled), coalesced store.
__global__ __launch_bounds__(256, 4) void conv_bin(
    const float* __restrict__ x,          // [N_NODES, 16]
    const uint2* __restrict__ rec,        // binned records
    const unsigned* __restrict__ cnt_arr, // [NB] counts (= cursors after scatter)
    const float* __restrict__ weight,     // [4,4,16,16] = [cell][i][f]
    float* __restrict__ out)              // [N_NODES, 16] (fully overwritten)
{
    __shared__ float accs[NPB * F];       // 4 KB

    const int lane = threadIdx.x & 63;
    const int wid  = threadIdx.x >> 6;
    const int e15  = lane & 15;        // D col: edge slot in 16-edge unit
    const int fo   = lane & 15;        // A row: output feature (weight frag)
    const int c    = lane >> 4;        // K-chunk 0..3
    const int hv   = c >> 1;
    const int i0   = (c & 1) * 8;

    // A fragments (weights), loaded once. MFMA m covers cells 2m, 2m+1.
    bf16x8 bw[8];
#pragma unroll
    for (int m = 0; m < 8; ++m) {
        const float* wp = weight + (2 * m + hv) * 256 + i0 * 16 + fo;
        union { bf16x8 v; unsigned w[4]; } bb;
#pragma unroll
        for (int p = 0; p < 4; ++p)
            bb.w[p] = pk_bf16(wp[(2 * p) * 16], wp[(2 * p + 1) * 16]);
        bw[m] = bb.v;
    }

    const int b = blockIdx.x;
    const unsigned cu = cnt_arr[b];
    const int cnt = (int)(cu < (unsigned)CAP ? cu : (unsigned)CAP);
    const uint2* recb = rec + (size_t)b * CAP;

    for (int i = threadIdx.x; i < NPB * F; i += 256) accs[i] = 0.f;
    __syncthreads();

    // ---- pipelined wave loop: 32 edges/iter (2 x 16-edge MFMA units) ----
    int j = wid * 32;
    uint2 r0[2], r1[2];
    float4 xa0[2], xb0[2];
    if (j < cnt) {
#pragma unroll
        for (int u = 0; u < 2; ++u) {
            int ia = j + u * 16 + e15;        ia = ia < cnt ? ia : cnt - 1;
            r0[u] = recb[ia];
            int ib = j + 128 + u * 16 + e15;  ib = ib < cnt ? ib : cnt - 1;
            r1[u] = recb[ib];
        }
#pragma unroll
        for (int u = 0; u < 2; ++u) {
            const int col = (int)(r0[u].x & 0x1FFFFu);
            const float4* xv = (const float4*)(x + (size_t)col * 16 + i0);
            xa0[u] = xv[0]; xb0[u] = xv[1];
        }
    }

    for (; j < cnt; j += 128) {
        // x prefetch for next chunk (cols resident in r1)
        float4 xa1[2], xb1[2];
#pragma unroll
        for (int u = 0; u < 2; ++u) {
            const int col = (int)(r1[u].x & 0x1FFFFu);
            const float4* xv = (const float4*)(x + (size_t)col * 16 + i0);
            xa1[u] = xv[0]; xb1[u] = xv[1];
        }
        // rec prefetch 2 chunks ahead (clamped)
        uint2 r2[2];
#pragma unroll
        for (int u = 0; u < 2; ++u) {
            int ic = j + 256 + u * 16 + e15;  ic = ic < cnt ? ic : cnt - 1;
            r2[u] = recb[ic];
        }

        // ---- compute current chunk ----
        float bu_[2][4], bvE_[2], bvO_[2];
        int ln[2];
#pragma unroll
        for (int u = 0; u < 2; ++u) {
            const int idx = j + u * 16 + e15;
            const float vm = idx < cnt ? 1.f : 0.f;   // mask tail lanes
            ln[u] = (int)((r0[u].x >> 17) & 63u);
            const float ax = f16lo(r0[u].y);
            const float ay = f16lo(r0[u].y >> 16);

            float fu = (ax + 1.0f) * 1.5f;
            int iu = (int)fu; iu = iu < 0 ? 0 : (iu > 2 ? 2 : iu);
            const float wu1 = fu - (float)iu, wu0 = 1.0f - wu1;
            float fv = (ay + 1.0f) * 1.5f;
            int iv = (int)fv; iv = iv < 0 ? 0 : (iv > 2 ? 2 : iv);
            const float wv1 = fv - (float)iv, wv0 = 1.0f - wv1;

            bu_[u][0] = iu == 0 ? wu0 : 0.f;
            bu_[u][1] = iu == 0 ? wu1 : (iu == 1 ? wu0 : 0.f);
            bu_[u][2] = iu == 2 ? wu0 : (iu == 1 ? wu1 : 0.f);
            bu_[u][3] = iu == 2 ? wu1 : 0.f;
            const float bv0 = iv == 0 ? wv0 : 0.f;
            const float bv1 = iv == 0 ? wv1 : (iv == 1 ? wv0 : 0.f);
            const float bv2 = iv == 2 ? wv0 : (iv == 1 ? wv1 : 0.f);
            const float bv3 = iv == 2 ? wv1 : 0.f;
            bvE_[u] = (hv ? bv1 : bv0) * vm;
            bvO_[u] = (hv ? bv3 : bv2) * vm;
        }

        f32x4 accE[2] = {{0.f,0.f,0.f,0.f},{0.f,0.f,0.f,0.f}};
        f32x4 accO[2] = {{0.f,0.f,0.f,0.f},{0.f,0.f,0.f,0.f}};
#pragma unroll
        for (int m = 0; m < 8; ++m) {
#pragma unroll
            for (int u = 0; u < 2; ++u) {
                const float t = bu_[u][m >> 1] * ((m & 1) ? bvO_[u] : bvE_[u]);
                union { bf16x8 v; unsigned w[4]; } aa;
                aa.w[0] = pk_bf16(t * xa0[u].x, t * xa0[u].y);
                aa.w[1] = pk_bf16(t * xa0[u].z, t * xa0[u].w);
                aa.w[2] = pk_bf16(t * xb0[u].x, t * xb0[u].y);
                aa.w[3] = pk_bf16(t * xb0[u].z, t * xb0[u].w);
                if (m & 1)
                    accO[u] = __builtin_amdgcn_mfma_f32_16x16x32_bf16(bw[m], aa.v, accO[u], 0, 0, 0);
                else
                    accE[u] = __builtin_amdgcn_mfma_f32_16x16x32_bf16(bw[m], aa.v, accE[u], 0, 0, 0);
            }
        }

        // LDS accumulate, XOR bank-swizzle: phys f = f ^ (loc&15)
#pragma unroll
        for (int u = 0; u < 2; ++u) {
            const f32x4 acc = accE[u] + accO[u];
            const int lx = ln[u] & 15;
            float* p = &accs[ln[u] * F];
            atomicAdd(p + ((c * 4 + 0) ^ lx), acc.x);
            atomicAdd(p + ((c * 4 + 1) ^ lx), acc.y);
            atomicAdd(p + ((c * 4 + 2) ^ lx), acc.z);
            atomicAdd(p + ((c * 4 + 3) ^ lx), acc.w);
        }

        // shift pipeline
#pragma unroll
        for (int u = 0; u < 2; ++u) {
            r0[u] = r1[u]; r1[u] = r2[u];
            xa0[u] = xa1[u]; xb0[u] = xb1[u];
        }
    }

    __syncthreads();
    // coalesced store, unswizzling: stored f at accs[loc*16 + (f ^ (loc&15))]
    const int nrem = N_NODES - b * NPB;
    const int nfl = (nrem < NPB ? nrem : NPB) * F;
    float* ob = out + (size_t)b * NPB * F;
    for (int i = threadIdx.x; i < nfl; i += 256) {
        const int loc = i >> 4, f = i & 15;
        ob[i] = accs[loc * F + (f ^ (loc & 15))];
    }
}

extern "C" void kernel_launch(void* const* d_in, const int* in_sizes, int n_in,
                              void* d_out, int out_size, void* d_ws, size_t ws_size,
                              hipStream_t stream) {
    const float* x  = (const float*)d_in[0];
    const int*   ei = (const int*)d_in[1];
    const float* ea = (const float*)d_in[2];
    const float* w  = (const float*)d_in[3];
    float* out = (float*)d_out;
    (void)out_size; (void)ws_size; (void)in_sizes; (void)n_in;

    uint2*    rec = (uint2*)d_ws;                              // 16.0 MB
    unsigned* cur = (unsigned*)d_ws + (size_t)NB * CAP * 2;    // 6.3 KB after rec

    zero_cur_kernel<<<(NB + 255) / 256, 256, 0, stream>>>(cur);
    scatter_kernel<<<2048, 256, 0, stream>>>(ei, (const float2*)ea, cur, rec);
    conv_bin<<<NB, 256, 0, stream>>>(x, rec, cur, w, out);
}

// Round 12
// 302.754 us; speedup vs baseline: 1.6707x; 1.5779x over previous
//
#include <hip/hip_runtime.h>

#define N_NODES 100000
#define N_EDGES 1600000
#define F 16

// 512 edges per block: 4 waves x 4 iterations x 32 edges. 1.6M/512 = 3125 blocks.
#define EDGES_PER_BLOCK 512
#define ITERS 4

#define WS_ELEMS (N_NODES * F)           // 1.6M bf16 accumulators (3.2 MB in d_ws)
#define WS_UINT4 (WS_ELEMS / 8)          // 200000 uint4s
#define CVT_THREADS (WS_ELEMS / 8)       // 8 bf16 per thread

typedef __attribute__((ext_vector_type(8))) short bf16x8;  // 8 bf16 (4 VGPRs)
typedef __attribute__((ext_vector_type(4))) float f32x4;   // MFMA C/D

__global__ __launch_bounds__(256) void zero_ws_kernel(uint4* __restrict__ ws) {
    int i = blockIdx.x * 256 + threadIdx.x;
    if (i < WS_UINT4) ws[i] = make_uint4(0u, 0u, 0u, 0u);
}

// Expand bf16 accumulator -> f32 output (overwrites ALL of out; no out zeroing).
__global__ __launch_bounds__(256) void ws_to_out_kernel(const uint4* __restrict__ ws,
                                                        float4* __restrict__ out) {
    int i = blockIdx.x * 256 + threadIdx.x;
    if (i >= CVT_THREADS) return;
    const uint4 v = ws[i];
    float4 a, b;
    a.x = __builtin_bit_cast(float, v.x << 16);
    a.y = __builtin_bit_cast(float, v.x & 0xffff0000u);
    a.z = __builtin_bit_cast(float, v.y << 16);
    a.w = __builtin_bit_cast(float, v.y & 0xffff0000u);
    b.x = __builtin_bit_cast(float, v.z << 16);
    b.y = __builtin_bit_cast(float, v.z & 0xffff0000u);
    b.z = __builtin_bit_cast(float, v.w << 16);
    b.w = __builtin_bit_cast(float, v.w & 0xffff0000u);
    out[2 * i + 0] = a;
    out[2 * i + 1] = b;
}

// pack two f32 -> one dword of 2 bf16 (RNE), single instruction.
__device__ __forceinline__ unsigned pk_bf16(float lo, float hi) {
    unsigned r;
    asm("v_cvt_pk_bf16_f32 %0, %1, %2" : "=v"(r) : "v"(lo), "v"(hi));
    return r;
}

// Accumulate (dx,dy) into a packed-bf16x2 dword via CAS. CAS is a classic
// full-rate atomic (unlike microcoded pk_add_bf16/u64-add): 2 CAS dword-ops
// per lane replace 4 f32 dword-adds. No livelock: if the add rounds back to
// the old value, nw == old and the CAS trivially succeeds; intra-wave
// same-address collisions retire one lane per retry under the exec mask.
__device__ __forceinline__ void cas_acc_bf16x2(unsigned* p, float dx, float dy) {
    unsigned old = __hip_atomic_load(p, __ATOMIC_RELAXED, __HIP_MEMORY_SCOPE_AGENT);
    while (true) {
        const float lo = __builtin_bit_cast(float, old << 16);
        const float hi = __builtin_bit_cast(float, old & 0xffff0000u);
        const unsigned nw = pk_bf16(lo + dx, hi + dy);
        const unsigned prev = atomicCAS(p, old, nw);
        if (prev == old) return;
        old = prev;
    }
}

// r3-r10 matrix: f32 dword-adds pin at 1/channel/cycle (25.6M -> 83us wall);
// pk_add_bf16 and u64-add are microcoded slow paths; packed-f32 add doesn't
// exist; sort-based grouping costs MORE than the wall (r9: 350us, r10:
// scatter alone 241us, pure cursor-atomic serialization). This round (resub
// of r11 after infra failure): same r5/r6-verified pipelined conv body,
// epilogue swapped to CAS-packed-bf16x2 -> 12.8M full-rate CAS ops (~47us of
// channel work) instead of 25.6M adds.
__global__ __launch_bounds__(256, 4) void basis_conv_mfma(
    const float* __restrict__ x,          // [N_NODES, 16]
    const int*   __restrict__ edge_index, // [2, N_EDGES] (int32 on device)
    const float* __restrict__ edge_attr,  // [N_EDGES, 2]
    const float* __restrict__ weight,     // [4,4,16,16] = [cell][i][f]
    unsigned*    __restrict__ ws)         // [N_NODES, 8] bf16x2 dwords, pre-zeroed
{
    const int lane = threadIdx.x & 63;
    const int wid  = threadIdx.x >> 6;
    const int e15  = lane & 15;        // B col: edge within 16-edge unit
    const int fo   = lane & 15;        // A row: output feature (weight frag)
    const int c    = lane >> 4;        // K-chunk 0..3 within each MFMA
    const int hv   = c >> 1;           // 0: even cell of the pair, 1: odd cell
    const int i0   = (c & 1) * 8;      // input-feature offset within cell

    // --- A fragments (weights), loaded once. MFMA m covers cells 2m, 2m+1.
    bf16x8 bw[8];
#pragma unroll
    for (int m = 0; m < 8; ++m) {
        const float* wp = weight + (2 * m + hv) * 256 + i0 * 16 + fo;
        union { bf16x8 v; unsigned w[4]; } bb;
#pragma unroll
        for (int p = 0; p < 4; ++p)
            bb.w[p] = pk_bf16(wp[(2 * p) * 16], wp[(2 * p + 1) * 16]);
        bw[m] = bb.v;
    }

    const int wbase = blockIdx.x * EDGES_PER_BLOCK + wid * (32 * ITERS);

    // ---- pipeline state (col/attr 2-deep, x 1-deep, dst-row 0-deep) ----
    float2 at0[2], at1[2];
    int    col1[2];
    float4 xa0[2], xb0[2];
    {
#pragma unroll
        for (int u = 0; u < 2; ++u) {
            const int egA = wbase + u * 16;            // iter 0
            const int col0 = edge_index[N_EDGES + egA + e15];
            at0[u] = ((const float2*)edge_attr)[egA + e15];
            const float4* xv = (const float4*)(x + (size_t)col0 * 16 + i0);
            xa0[u] = xv[0]; xb0[u] = xv[1];
            const int egB = wbase + 32 + u * 16;       // iter 1 (< N_EDGES always)
            col1[u] = edge_index[N_EDGES + egB + e15];
            at1[u]  = ((const float2*)edge_attr)[egB + e15];
        }
    }

#pragma unroll 1
    for (int g = 0; g < ITERS; ++g) {
        // dst rows for CURRENT iter: issued first (oldest vmcnt), consumed
        // after the whole compute phase -> latency fully covered.
        int rowd[2];
#pragma unroll
        for (int u = 0; u < 2; ++u)
            rowd[u] = edge_index[wbase + g * 32 + u * 16 + e15];

        // x prefetch for iter g+1 (cols already resident)
        float4 xa1[2], xb1[2];
#pragma unroll
        for (int u = 0; u < 2; ++u) {
            const float4* xv = (const float4*)(x + (size_t)col1[u] * 16 + i0);
            xa1[u] = xv[0]; xb1[u] = xv[1];
        }

        // meta prefetch for iter g+2 (clamped; results unused on last iters)
        int col2[2]; float2 at2[2];
#pragma unroll
        for (int u = 0; u < 2; ++u) {
            int eg2 = wbase + (g + 2) * 32 + u * 16;
            eg2 = eg2 > (N_EDGES - 16) ? (N_EDGES - 16) : eg2;
            col2[u] = edge_index[N_EDGES + eg2 + e15];
            at2[u]  = ((const float2*)edge_attr)[eg2 + e15];
        }

        // ---- basis factors ----
        float bu_[2][4], bvE_[2], bvO_[2];
#pragma unroll
        for (int u = 0; u < 2; ++u) {
            float fu = (at0[u].x + 1.0f) * 1.5f;
            int iu = (int)fu; iu = iu < 0 ? 0 : (iu > 2 ? 2 : iu);
            const float wu1 = fu - (float)iu, wu0 = 1.0f - wu1;
            float fv = (at0[u].y + 1.0f) * 1.5f;
            int iv = (int)fv; iv = iv < 0 ? 0 : (iv > 2 ? 2 : iv);
            const float wv1 = fv - (float)iv, wv0 = 1.0f - wv1;

            bu_[u][0] = iu == 0 ? wu0 : 0.f;
            bu_[u][1] = iu == 0 ? wu1 : (iu == 1 ? wu0 : 0.f);
            bu_[u][2] = iu == 2 ? wu0 : (iu == 1 ? wu1 : 0.f);
            bu_[u][3] = iu == 2 ? wu1 : 0.f;
            const float bv0 = iv == 0 ? wv0 : 0.f;
            const float bv1 = iv == 0 ? wv1 : (iv == 1 ? wv0 : 0.f);
            const float bv2 = iv == 2 ? wv0 : (iv == 1 ? wv1 : 0.f);
            const float bv3 = iv == 2 ? wv1 : 0.f;
            bvE_[u] = hv ? bv1 : bv0;  // m even
            bvO_[u] = hv ? bv3 : bv2;  // m odd
        }

        // ---- 16 MFMAs, 4 independent chains; D = W(16f x 32K) * X(32K x 16e)
        f32x4 accE[2] = {{0.f,0.f,0.f,0.f},{0.f,0.f,0.f,0.f}};
        f32x4 accO[2] = {{0.f,0.f,0.f,0.f},{0.f,0.f,0.f,0.f}};
#pragma unroll
        for (int m = 0; m < 8; ++m) {
#pragma unroll
            for (int u = 0; u < 2; ++u) {
                const float t = bu_[u][m >> 1] * ((m & 1) ? bvO_[u] : bvE_[u]);
                union { bf16x8 v; unsigned w[4]; } aa;
                aa.w[0] = pk_bf16(t * xa0[u].x, t * xa0[u].y);
                aa.w[1] = pk_bf16(t * xa0[u].z, t * xa0[u].w);
                aa.w[2] = pk_bf16(t * xb0[u].x, t * xb0[u].y);
                aa.w[3] = pk_bf16(t * xb0[u].z, t * xb0[u].w);
                if (m & 1)
                    accO[u] = __builtin_amdgcn_mfma_f32_16x16x32_bf16(bw[m], aa.v, accO[u], 0, 0, 0);
                else
                    accE[u] = __builtin_amdgcn_mfma_f32_16x16x32_bf16(bw[m], aa.v, accE[u], 0, 0, 0);
            }
        }

        // D layout (swapped, r6-verified): lane holds features c*4+{0..3} of
        // edge e15. Two CAS-packed dwords per lane (8 CAS ops per edge).
#pragma unroll
        for (int u = 0; u < 2; ++u) {
            const f32x4 acc = accE[u] + accO[u];
            unsigned* p = ws + (size_t)rowd[u] * 8 + c * 2;
            cas_acc_bf16x2(p + 0, acc.x, acc.y);
            cas_acc_bf16x2(p + 1, acc.z, acc.w);
        }

        // ---- shift pipeline ----
#pragma unroll
        for (int u = 0; u < 2; ++u) {
            at0[u] = at1[u];
            xa0[u] = xa1[u]; xb0[u] = xb1[u];
            col1[u] = col2[u]; at1[u] = at2[u];
        }
    }
}

extern "C" void kernel_launch(void* const* d_in, const int* in_sizes, int n_in,
                              void* d_out, int out_size, void* d_ws, size_t ws_size,
                              hipStream_t stream) {
    const float* x  = (const float*)d_in[0];
    const int*   ei = (const int*)d_in[1];
    const float* ea = (const float*)d_in[2];
    const float* w  = (const float*)d_in[3];
    float* out = (float*)d_out;
    unsigned* ws = (unsigned*)d_ws;
    (void)out_size; (void)ws_size; (void)in_sizes; (void)n_in;

    zero_ws_kernel<<<(WS_UINT4 + 255) / 256, 256, 0, stream>>>((uint4*)ws);

    const int blocks = N_EDGES / EDGES_PER_BLOCK;  // 3125
    basis_conv_mfma<<<blocks, 256, 0, stream>>>(x, ei, ea, w, ws);

    ws_to_out_kernel<<<(CVT_THREADS + 255) / 256, 256, 0, stream>>>(
        (const uint4*)ws, (float4*)out);
}

// Round 13
// 161.933 us; speedup vs baseline: 3.1236x; 1.8696x over previous
//
#include <hip/hip_runtime.h>

#define N_NODES 100000
#define N_EDGES 1600000
#define F 16

// 512 edges per block: 4 waves x 8 groups of 16 edges. 1.6M/512 = 3125 blocks.
#define EDGES_PER_BLOCK 512
#define GROUPS_PER_WAVE 8

#define OUT_FLOAT4 ((N_NODES * F) / 4)   // 400000

typedef __attribute__((ext_vector_type(8))) short bf16x8;  // 8 bf16 (4 VGPRs)
typedef __attribute__((ext_vector_type(4))) float f32x4;   // MFMA C/D

__global__ __launch_bounds__(256) void zero_out_kernel(float4* __restrict__ out) {
    int i = blockIdx.x * 256 + threadIdx.x;
    if (i < OUT_FLOAT4) out[i] = make_float4(0.f, 0.f, 0.f, 0.f);
}

// pack two f32 -> one dword of 2 bf16 (RNE), single instruction.
__device__ __forceinline__ unsigned pk_bf16(float lo, float hi) {
    unsigned r;
    asm("v_cvt_pk_bf16_f32 %0, %1, %2" : "=v"(r) : "v"(lo), "v"(hi));
    return r;
}

// BEST VERIFIED KERNEL (round 4: bench 162.1us, conv 87.5us, absmax 0.0078).
//
// Structure: MFMA over K=256 basis-expanded inputs, weights resident in 32
// VGPRs (zero LDS), 2-deep software pipeline (idx/attr 2 ahead, x-gather 1
// ahead, dest rows loaded at iteration top as oldest vmcnt entry).
//
// This kernel runs at 95% of the measured dword-atomic coherence-point wall:
// 25.6M f32 dword atomics at 1/channel/cycle (128 ch x 2.4GHz) = 83us.
// COMPLETE exploration matrix (all measured, rounds 3-12):
//   f32 dword add x16/edge  ->  87-90us  (fast path; THIS kernel)
//   pk_add_bf16  x8/edge    ->  166us    (microcoded, 3.7x slower/op)
//   u64 add      x8/edge    ->  147us    (microcoded, 2x write-amp)
//   pk_add_f32              ->  n/a      (instruction doesn't exist on gfx950)
//   CAS bf16x2   x8/edge    ->  230us    (returning-atomic + retry traffic)
//   hist+scan+sort + LDS    ->  506us    (grouping costs >> the wall)
//   fixed-cap bin + LDS     ->  478us    (cursor serialization, write-amp)
// Dedup can't help (512 random dests over 100K nodes ~= all distinct);
// replication doesn't reduce RMW op count. This is the atomic-op roofline.
__global__ __launch_bounds__(256) void basis_conv_mfma(
    const float* __restrict__ x,          // [N_NODES, 16]
    const int*   __restrict__ edge_index, // [2, N_EDGES] (int32 on device)
    const float* __restrict__ edge_attr,  // [N_EDGES, 2]
    const float* __restrict__ weight,     // [4,4,16,16] = [cell][i][f]
    float*       __restrict__ out)        // [N_NODES, 16], pre-zeroed
{
    const int lane = threadIdx.x & 63;
    const int wid  = threadIdx.x >> 6;
    const int e15  = lane & 15;        // A-row: edge within group
    const int fo   = lane & 15;        // B/D col: output feature
    const int c    = lane >> 4;        // K-chunk 0..3 within each MFMA
    const int hv   = c >> 1;           // 0: even cell of the pair, 1: odd cell
    const int i0   = (c & 1) * 8;      // input-feature offset within cell

    // --- B fragments (weights), loaded once. MFMA m covers cells 2m, 2m+1.
    bf16x8 bw[8];
#pragma unroll
    for (int m = 0; m < 8; ++m) {
        const float* wp = weight + (2 * m + hv) * 256 + i0 * 16 + fo;
        union { bf16x8 v; unsigned u[4]; } bb;
#pragma unroll
        for (int p = 0; p < 4; ++p)
            bb.u[p] = pk_bf16(wp[(2 * p) * 16], wp[(2 * p + 1) * 16]);
        bw[m] = bb.v;
    }

    const int wbase = blockIdx.x * EDGES_PER_BLOCK + wid * (16 * GROUPS_PER_WAVE);

    // ---- 2-deep pipeline state ----
    int col0, col1; float2 at0, at1; int4 r40, r41;
    float4 xa0, xb0;
    {
        const int eg0 = wbase;
        col0 = edge_index[N_EDGES + eg0 + e15];
        at0  = ((const float2*)edge_attr)[eg0 + e15];
        r40  = *(const int4*)(edge_index + eg0 + 4 * c);
        const float4* xv = (const float4*)(x + (size_t)col0 * 16 + i0);
        xa0 = xv[0]; xb0 = xv[1];
        const int eg1 = wbase + 16;            // always < N_EDGES (wbase <= 1599872)
        col1 = edge_index[N_EDGES + eg1 + e15];
        at1  = ((const float2*)edge_attr)[eg1 + e15];
        r41  = *(const int4*)(edge_index + eg1 + 4 * c);
    }

#pragma unroll 1
    for (int g = 0; g < GROUPS_PER_WAVE; ++g) {
        // issue stage-1 x gather (col1 resident from previous iteration)
        const float4* xv1 = (const float4*)(x + (size_t)col1 * 16 + i0);
        const float4 xa1 = xv1[0], xb1 = xv1[1];

        // issue stage-2 idx/attr/rows (clamped: beyond-grid prefetch reads
        // valid neighbor edges; results unused on the last groups)
        int eg2 = wbase + (g + 2) * 16;
        eg2 = eg2 > (N_EDGES - 16) ? (N_EDGES - 16) : eg2;
        const int   col2 = edge_index[N_EDGES + eg2 + e15];
        const float2 at2 = ((const float2*)edge_attr)[eg2 + e15];
        const int4  r42  = *(const int4*)(edge_index + eg2 + 4 * c);

        // ---- compute on stage-0 (all operands already in registers) ----
        float fu = (at0.x + 1.0f) * 1.5f;
        int iu = (int)fu; iu = iu < 0 ? 0 : (iu > 2 ? 2 : iu);
        const float wu1 = fu - (float)iu, wu0 = 1.0f - wu1;
        float fv = (at0.y + 1.0f) * 1.5f;
        int iv = (int)fv; iv = iv < 0 ? 0 : (iv > 2 ? 2 : iv);
        const float wv1 = fv - (float)iv, wv0 = 1.0f - wv1;

        const float bu0 = iu == 0 ? wu0 : 0.f;
        const float bu1 = iu == 0 ? wu1 : (iu == 1 ? wu0 : 0.f);
        const float bu2 = iu == 2 ? wu0 : (iu == 1 ? wu1 : 0.f);
        const float bu3 = iu == 2 ? wu1 : 0.f;
        const float bv0 = iv == 0 ? wv0 : 0.f;
        const float bv1 = iv == 0 ? wv1 : (iv == 1 ? wv0 : 0.f);
        const float bv2 = iv == 2 ? wv0 : (iv == 1 ? wv1 : 0.f);
        const float bv3 = iv == 2 ? wv1 : 0.f;

        const float bvE = hv ? bv1 : bv0;  // m even
        const float bvO = hv ? bv3 : bv2;  // m odd

        f32x4 acc0 = {0.f, 0.f, 0.f, 0.f};
        f32x4 acc1 = {0.f, 0.f, 0.f, 0.f};
#pragma unroll
        for (int m = 0; m < 8; ++m) {
            const float bu = (m >> 1) == 0 ? bu0 : (m >> 1) == 1 ? bu1
                           : (m >> 1) == 2 ? bu2 : bu3;
            const float t = bu * ((m & 1) ? bvO : bvE);
            union { bf16x8 v; unsigned u[4]; } aa;
            aa.u[0] = pk_bf16(t * xa0.x, t * xa0.y);
            aa.u[1] = pk_bf16(t * xa0.z, t * xa0.w);
            aa.u[2] = pk_bf16(t * xb0.x, t * xb0.y);
            aa.u[3] = pk_bf16(t * xb0.z, t * xb0.w);
            if (m & 1)
                acc1 = __builtin_amdgcn_mfma_f32_16x16x32_bf16(aa.v, bw[m], acc1, 0, 0, 0);
            else
                acc0 = __builtin_amdgcn_mfma_f32_16x16x32_bf16(aa.v, bw[m], acc0, 0, 0, 0);
        }
        const f32x4 acc = acc0 + acc1;

        // D layout: row = c*4 + reg (edge in group), col = lane&15 (out feature)
        unsafeAtomicAdd(out + (size_t)r40.x * 16 + fo, acc.x);
        unsafeAtomicAdd(out + (size_t)r40.y * 16 + fo, acc.y);
        unsafeAtomicAdd(out + (size_t)r40.z * 16 + fo, acc.z);
        unsafeAtomicAdd(out + (size_t)r40.w * 16 + fo, acc.w);

        // ---- shift pipeline (waitcnt for the prefetch loads lands here,
        //      after a full iteration of latency cover) ----
        col0 = col1; at0 = at1; r40 = r41;
        xa0 = xa1;  xb0 = xb1;
        col1 = col2; at1 = at2; r41 = r42;
    }
}

extern "C" void kernel_launch(void* const* d_in, const int* in_sizes, int n_in,
                              void* d_out, int out_size, void* d_ws, size_t ws_size,
                              hipStream_t stream) {
    const float* x  = (const float*)d_in[0];
    const int*   ei = (const int*)d_in[1];
    const float* ea = (const float*)d_in[2];
    const float* w  = (const float*)d_in[3];
    float* out = (float*)d_out;
    (void)out_size; (void)d_ws; (void)ws_size; (void)in_sizes; (void)n_in;

    zero_out_kernel<<<(OUT_FLOAT4 + 255) / 256, 256, 0, stream>>>((float4*)out);

    const int blocks = N_EDGES / EDGES_PER_BLOCK;  // 3125
    basis_conv_mfma<<<blocks, 256, 0, stream>>>(x, ei, ea, w, out);
}